// Round 3
// baseline (958.647 us; speedup 1.0000x reference)
//
#include <hip/hip_runtime.h>
#include <math.h>
#include <stdint.h>

#define B_ 4
#define C_ 256
#define H_ 128
#define W_ 128
#define NPIX (H_*W_)

typedef short bf16x8 __attribute__((ext_vector_type(8)));
typedef int   i32x4  __attribute__((ext_vector_type(4)));
typedef float f32x4  __attribute__((ext_vector_type(4)));

#define XBYTES 82944            // 324 halo slots * 256 B (128 c as bf16, swizzled)
#define WOFF   XBYTES
#define WSLICE 32768            // 256 o * 64 c * 2 B
#define LDS_TOTAL (XBYTES + 2*WSLICE)   // 148480 <= 163840

__device__ __forceinline__ unsigned short f2bf_rne(float v) {
    uint32_t b = __float_as_uint(v);
    return (unsigned short)((b + 0x7fff + ((b >> 16) & 1)) >> 16);
}

// ---- prep: 36 W slices, stream order s = ch*18 + k*2 + q.
// Slice image element [o][u'][e], u' = u ^ (o&7), c = ch*128 + q*64 + u*8 + e.
__global__ __launch_bounds__(256)
void prep_w(const float* __restrict__ wg, unsigned short* __restrict__ wb) {
    int f = blockIdx.x * 256 + threadIdx.x;       // < 589824
    int s = f >> 14;
    int within = f & 16383;
    int o = within >> 6;
    int t = within & 63;
    int up = t >> 3;
    int e = t & 7;
    int ch = s / 18;
    int r = s - ch * 18;
    int k = r >> 1;
    int q = r & 1;
    int u = up ^ (o & 7);
    int c = ch * 128 + q * 64 + u * 8 + e;
    wb[f] = f2bf_rne(wg[(o * C_ + c) * 9 + k]);
}

// ---- main step: 256-pixel tiles, counted-vmcnt W pipeline, mask-on-B
__global__ __launch_bounds__(512, 2)
void nca_v3(const float* __restrict__ xin,
            const unsigned short* __restrict__ wb,
            const float* __restrict__ mask,
            float* __restrict__ xout)
{
    extern __shared__ char smem[];
    const int tid = threadIdx.x;
    const int l   = tid & 63;
    const int wid = tid >> 6;
    const int wave_o = wid & 3;      // 64 o each
    const int wave_p = wid >> 2;     // 8 pixel-rows each
    const int g   = l >> 4;
    const int l15 = l & 15;

    const int bid = blockIdx.x;
    const int tc = bid & 7;
    const int tr = (bid >> 3) & 7;
    const int b  = bid >> 6;

    // ---- issue W slices 0 (buf0) and 1 (buf1) immediately
    #pragma unroll
    for (int j = 0; j < 4; ++j) {
        const int seg = j * 8192 + wid * 1024;
        __builtin_amdgcn_global_load_lds(
            (const __attribute__((address_space(1))) uint32_t*)((const char*)wb + seg + l * 16),
            (__attribute__((address_space(3))) uint32_t*)(smem + WOFF + seg), 16, 0, 0);
    }
    #pragma unroll
    for (int j = 0; j < 4; ++j) {
        const int seg = j * 8192 + wid * 1024;
        __builtin_amdgcn_global_load_lds(
            (const __attribute__((address_space(1))) uint32_t*)((const char*)wb + WSLICE + seg + l * 16),
            (__attribute__((address_space(3))) uint32_t*)(smem + WOFF + WSLICE + seg), 16, 0, 0);
    }

    // ---- mask bits for this lane: 9 taps x 8 rows, packed (binary mask)
    unsigned long long mlo = 0ull;
    unsigned int mhi = 0u;
    {
        const int mrow0 = tr * 16 + wave_p * 8;
        const int mcol  = tc * 16 + l15;
        #pragma unroll
        for (int k = 0; k < 9; ++k) {
            #pragma unroll
            for (int n = 0; n < 8; ++n) {
                unsigned int bit = (mask[k * NPIX + (mrow0 + n) * W_ + mcol] != 0.f) ? 1u : 0u;
                if (k < 8) mlo |= ((unsigned long long)bit) << (k * 8 + n);
                else       mhi |= (bit << n);
            }
        }
    }

    f32x4 acc[4][8];
    #pragma unroll
    for (int m = 0; m < 4; ++m)
        #pragma unroll
        for (int n = 0; n < 8; ++n) acc[m][n] = (f32x4){0.f, 0.f, 0.f, 0.f};

    int sbase[8];
    #pragma unroll
    for (int n = 0; n < 8; ++n) sbase[n] = (wave_p * 8 + n) * 18 + l15;

    const float* xbatch = xin + (size_t)b * C_ * NPIX;
    const int grp = l / 6;          // 6-lane groups, 10 per wave (lanes 60-63 idle)
    const int sub = l - grp * 6;

    #pragma unroll 1
    for (int ch = 0; ch < 2; ++ch) {
        // ---- stage x half ch: fp32 -> bf16, swizzled slot layout
        if (grp < 10) {
            #pragma unroll 1
            for (int it = 0; it < 29; ++it) {
                int p = it * 80 + wid * 10 + grp;      // (c_loc, rr) pair
                if (p < 2304) {
                    int c_loc = p / 18;
                    int rr = p - c_loc * 18;
                    int gh = tr * 16 + rr - 1;
                    int gwb = tc * 16 - 4 + sub * 4;   // 24-col window covers halo cols -1..16
                    int gwc = min(max(gwb, 0), 124);
                    float4 v = make_float4(0.f, 0.f, 0.f, 0.f);
                    bool rowok = ((unsigned)gh < 128u);
                    if (rowok)
                        v = *(const float4*)(xbatch + ((size_t)(ch * 128 + c_loc) * H_ + gh) * W_ + gwc);
                    const float* ve = (const float*)&v;
                    #pragma unroll
                    for (int e = 0; e < 4; ++e) {
                        int gw = gwb + e;
                        int hc = gw - tc * 16 + 1;     // halo col
                        if ((unsigned)hc < 18u) {
                            float val = (rowok && (unsigned)gw < 128u) ? ve[e] : 0.f;
                            int s = rr * 18 + hc;
                            int off = s * 256 + (((c_loc >> 3) ^ (s & 7)) << 4) + (c_loc & 7) * 2;
                            *(unsigned short*)(smem + off) = f2bf_rne(val);
                        }
                    }
                }
            }
        }
        asm volatile("s_waitcnt lgkmcnt(0)" ::: "memory");
        __builtin_amdgcn_sched_barrier(0);
        __builtin_amdgcn_s_barrier();

        #pragma unroll 1
        for (int k = 0; k < 9; ++k) {
            const int dy = (k * 11) >> 5;
            const int dx = k - dy * 3;
            const int doff = dy * 18 + dx;
            const unsigned int mk = (k < 8) ? (unsigned int)(mlo >> (k * 8)) : mhi;
            const int slbase = ch * 18 + k * 2;

            #pragma unroll
            for (int q = 0; q < 2; ++q) {
                const int sl = slbase + q;             // slice parity == q
                if (sl == 35) { asm volatile("s_waitcnt vmcnt(0)" ::: "memory"); }
                else          { asm volatile("s_waitcnt vmcnt(4)" ::: "memory"); }
                __builtin_amdgcn_sched_barrier(0);
                __builtin_amdgcn_s_barrier();

                const char* wbuf = smem + WOFF + (q ? WSLICE : 0);
                #pragma unroll
                for (int kk = 0; kk < 2; ++kk) {
                    bf16x8 av[4];
                    #pragma unroll
                    for (int m = 0; m < 4; ++m) {
                        int o_l = wave_o * 64 + m * 16 + l15;
                        av[m] = *(const bf16x8*)(wbuf + o_l * 128 + (((kk * 4 + g) ^ (o_l & 7)) << 4));
                    }
                    #pragma unroll
                    for (int n = 0; n < 8; ++n) {
                        int spx = sbase[n] + doff;
                        int u = q * 8 + kk * 4 + g;
                        i32x4 braw = *(const i32x4*)(smem + spx * 256 + ((u ^ (spx & 7)) << 4));
                        int mm = -(int)((mk >> n) & 1u);
                        braw &= mm;                    // binary mask, exact
                        bf16x8 bv = __builtin_bit_cast(bf16x8, braw);
                        #pragma unroll
                        for (int m = 0; m < 4; ++m)
                            acc[m][n] = __builtin_amdgcn_mfma_f32_16x16x32_bf16(av[m], bv, acc[m][n], 0, 0, 0);
                    }
                }
                asm volatile("" ::: "memory");
                __builtin_amdgcn_s_barrier();
                if (sl + 2 < 36) {                     // prefetch into freed buffer
                    const char* src = (const char*)wb + (size_t)(sl + 2) * WSLICE;
                    char* dstb = (char*)smem + WOFF + (q ? WSLICE : 0);
                    #pragma unroll
                    for (int j = 0; j < 4; ++j) {
                        const int seg = j * 8192 + wid * 1024;
                        __builtin_amdgcn_global_load_lds(
                            (const __attribute__((address_space(1))) uint32_t*)(src + seg + l * 16),
                            (__attribute__((address_space(3))) uint32_t*)(dstb + seg), 16, 0, 0);
                    }
                }
            }
        }
    }

    // ---- epilogue: residual + squash
    #pragma unroll
    for (int m = 0; m < 4; ++m) {
        #pragma unroll
        for (int n = 0; n < 8; ++n) {
            const int h = tr * 16 + wave_p * 8 + n;
            const int w = tc * 16 + l15;
            #pragma unroll
            for (int r = 0; r < 4; ++r) {
                const int o = wave_o * 64 + m * 16 + g * 4 + r;
                const size_t off = ((size_t)(b * C_ + o) * H_ + h) * W_ + w;
                const float d = acc[m][n][r];
                xout[off] = xin[off] + d / (1.f + fabsf(d));
            }
        }
    }
}

// ================= fp32 fallback (round-1 kernel, ws too small) =================
#define OT 64
#define TR 4
#define TC 16
#define CKC 16
__global__ __launch_bounds__(256)
void nca_step_f32(const float* __restrict__ xin, const float* __restrict__ wg,
                  const float* __restrict__ mask, float* __restrict__ xout)
{
    __shared__ __align__(16) float w_s[CKC][9][OT];
    __shared__ __align__(16) float x_s[CKC][TR + 2][20];
    const int tid = threadIdx.x;
    int bt = blockIdx.x;
    const int col_tile = bt & 7;  bt >>= 3;
    const int row_tile = bt & 31; bt >>= 5;
    const int ot = bt & 3;        const int b = bt >> 2;
    const int gr0 = row_tile * TR, gc0 = col_tile * TC, o_base = ot * OT;
    const int og = tid >> 4, pg = tid & 15;
    const int prow = pg >> 2, pcol4 = (pg & 3) * 4;
    const int orow = gr0 + prow, ocol0 = gc0 + pcol4;
    float mask_r[9][4];
#pragma unroll
    for (int k = 0; k < 9; ++k)
#pragma unroll
        for (int j = 0; j < 4; ++j)
            mask_r[k][j] = mask[k * NPIX + orow * W_ + (ocol0 + j)];
    float acc[4][4];
#pragma unroll
    for (int a = 0; a < 4; ++a)
#pragma unroll
        for (int j = 0; j < 4; ++j) acc[a][j] = 0.f;
    for (int chunk = 0; chunk < C_ / CKC; ++chunk) {
        const int c0 = chunk * CKC;
#pragma unroll
        for (int i = 0; i < 36; ++i) {
            const int flat = i * 256 + tid;
            const int o_l = flat / 144;
            const int r = flat - o_l * 144;
            const int c_l = r / 9;
            const int kk = r - c_l * 9;
            w_s[c_l][kk][o_l] = wg[(o_base + o_l) * (C_ * 9) + (c0 + c_l) * 9 + kk];
        }
#pragma unroll
        for (int i = 0; i < 7; ++i) {
            const int flat = i * 256 + tid;
            if (flat < CKC * 108) {
                const int c_l = flat / 108;
                const int r = flat - c_l * 108;
                const int row = r / 18, col = r - row * 18;
                const int grow = gr0 - 1 + row, gcol = gc0 - 1 + col;
                float v = 0.f;
                if ((unsigned)grow < (unsigned)H_ && (unsigned)gcol < (unsigned)W_)
                    v = xin[((b * C_ + c0 + c_l) * H_ + grow) * W_ + gcol];
                x_s[c_l][row][col] = v;
            }
        }
        __syncthreads();
#pragma unroll
        for (int dyy = 0; dyy < 3; ++dyy) {
            float acck[3][4][4];
#pragma unroll
            for (int dxx = 0; dxx < 3; ++dxx)
#pragma unroll
                for (int a = 0; a < 4; ++a)
#pragma unroll
                    for (int j = 0; j < 4; ++j) acck[dxx][a][j] = 0.f;
#pragma unroll 4
            for (int c = 0; c < CKC; ++c) {
                const float4 xv4 = *(const float4*)&x_s[c][prow + dyy][pcol4];
                const float2 xv2 = *(const float2*)&x_s[c][prow + dyy][pcol4 + 4];
                const float xv[6] = {xv4.x, xv4.y, xv4.z, xv4.w, xv2.x, xv2.y};
#pragma unroll
                for (int dxx = 0; dxx < 3; ++dxx) {
                    const float4 wv = *(const float4*)&w_s[c][dyy * 3 + dxx][og * 4];
                    const float wa[4] = {wv.x, wv.y, wv.z, wv.w};
#pragma unroll
                    for (int a = 0; a < 4; ++a)
#pragma unroll
                        for (int j = 0; j < 4; ++j)
                            acck[dxx][a][j] = fmaf(wa[a], xv[j + dxx], acck[dxx][a][j]);
                }
            }
#pragma unroll
            for (int dxx = 0; dxx < 3; ++dxx) {
                const int k = dyy * 3 + dxx;
#pragma unroll
                for (int a = 0; a < 4; ++a)
#pragma unroll
                    for (int j = 0; j < 4; ++j)
                        acc[a][j] = fmaf(mask_r[k][j], acck[dxx][a][j], acc[a][j]);
            }
        }
        __syncthreads();
    }
#pragma unroll
    for (int a = 0; a < 4; ++a) {
        const int o = o_base + og * 4 + a;
#pragma unroll
        for (int j = 0; j < 4; ++j) {
            const int idx = ((b * C_ + o) * H_ + orow) * W_ + (ocol0 + j);
            const float d = acc[a][j];
            xout[idx] = xin[idx] + d / (1.0f + fabsf(d));
        }
    }
}

extern "C" void kernel_launch(void* const* d_in, const int* in_sizes, int n_in,
                              void* d_out, int out_size, void* d_ws, size_t ws_size,
                              hipStream_t stream) {
    const float* retina = (const float*)d_in[0];
    const float* wg     = (const float*)d_in[1];
    const float* mask   = (const float*)d_in[2];
    float* out = (float*)d_out;

    const size_t xbytes = (size_t)B_ * C_ * NPIX * 4;    // 64 MiB ping-pong
    const size_t wb_reserve = 2u << 20;                  // 2 MiB for Wb

    if (ws_size >= wb_reserve + xbytes) {
        unsigned short* wb = (unsigned short*)d_ws;
        float* xpp = (float*)((char*)d_ws + wb_reserve);

        hipFuncSetAttribute((const void*)nca_v3,
                            hipFuncAttributeMaxDynamicSharedMemorySize, LDS_TOTAL);

        prep_w<<<2304, 256, 0, stream>>>(wg, wb);

        const float* src = retina;
        float* dsts[5] = {out, xpp, out, xpp, out};
        for (int s = 0; s < 5; ++s) {
            nca_v3<<<256, 512, LDS_TOTAL, stream>>>(src, wb, mask, dsts[s]);
            src = dsts[s];
        }
    } else {
        float* ws = (float*)d_ws;
        const int nblocks = B_ * (C_ / OT) * (H_ / TR) * (W_ / TC);
        const float* src = retina;
        float* dsts[5] = {out, ws, out, ws, out};
        for (int s = 0; s < 5; ++s) {
            nca_step_f32<<<dim3(nblocks), dim3(256), 0, stream>>>(src, wg, mask, dsts[s]);
            src = dsts[s];
        }
    }
}

// Round 4
// 605.541 us; speedup vs baseline: 1.5831x; 1.5831x over previous
//
#include <hip/hip_runtime.h>
#include <math.h>
#include <stdint.h>

#define B_ 4
#define C_ 256
#define H_ 128
#define W_ 128
#define NPIX (H_*W_)

typedef short bf16x8 __attribute__((ext_vector_type(8)));
typedef int   i32x4  __attribute__((ext_vector_type(4)));
typedef float f32x16 __attribute__((ext_vector_type(16)));
typedef unsigned short u16x4 __attribute__((ext_vector_type(4)));

// ---- LDS map (main kernel) ----
#define XSZ   41984              // 328 slots * 128 B (one 64-c quarter of 18x18 halo)
#define WOFF  (2*XSZ)            // 83968
#define WSL   32768              // one W slice: 256 o * 64 c * 2 B
#define SCR   (WOFF + 2*WSL)     // 149504: 1 KB scratch for padded stage ops
#define LDS_TOTAL (SCR + 1024)   // 150528 <= 163840

__device__ __forceinline__ unsigned short f2bf_rne(float v) {
    uint32_t b = __float_as_uint(v);
    return (unsigned short)((b + 0x7fff + ((b >> 16) & 1)) >> 16);
}
__device__ __forceinline__ float bf2f(unsigned short h) {
    return __uint_as_float(((uint32_t)h) << 16);
}

// ---- prep: 36 W slices, slice sl = qt*9 + k; image[o][u'][e] with u' = u ^ (o&7),
//      c = qt*64 + u*8 + e.  Block 2304 zeroes the 256-B zero block.
__global__ __launch_bounds__(256)
void prep_w(const float* __restrict__ wg, unsigned short* __restrict__ wb,
            unsigned short* __restrict__ zb) {
    if (blockIdx.x == 2304) { if (threadIdx.x < 128) zb[threadIdx.x] = 0; return; }
    int f = blockIdx.x * 256 + threadIdx.x;          // < 589824
    int sl = f >> 14, within = f & 16383;
    int o = within >> 6, t = within & 63;
    int up = t >> 3, e = t & 7;
    int qt = sl / 9, k = sl - qt * 9;
    int c = qt * 64 + ((up ^ (o & 7)) << 3) + e;
    wb[f] = f2bf_rne(wg[(o * C_ + c) * 9 + k]);
}

// ---- prep: retina fp32 (B,C,H,W) -> channel-last hi/lo bf16 shadows (B,H,W,C)
__global__ __launch_bounds__(256)
void prep_split(const float* __restrict__ retina, unsigned short* __restrict__ hi,
                unsigned short* __restrict__ lo) {
    __shared__ unsigned int t[64][65];
    int bid = blockIdx.x;
    const int wt = bid & 1;        bid >>= 1;
    const int h  = bid & 127;      bid >>= 7;
    const int ct = bid & 3;        const int b = bid >> 2;
    const int tid = threadIdx.x;
    const int ci4 = tid >> 6, wi = tid & 63;
    #pragma unroll
    for (int cc = 0; cc < 16; ++cc) {
        int c_loc = cc * 4 + ci4;
        float v = retina[((size_t)(b * C_ + ct * 64 + c_loc) * H_ + h) * W_ + wt * 64 + wi];
        unsigned short hv = f2bf_rne(v);
        unsigned short lv = f2bf_rne(v - bf2f(hv));
        t[c_loc][wi] = (unsigned)hv | ((unsigned)lv << 16);
    }
    __syncthreads();
    const int p = tid >> 2, j = tid & 3;
    size_t base = (((size_t)(b * H_ + h) * W_ + wt * 64 + p) << 8) + ct * 64 + j * 16;
    u16x4 hv4[4], lv4[4];
    #pragma unroll
    for (int e = 0; e < 16; ++e) {
        unsigned u = t[j * 16 + e][p];
        hv4[e >> 2][e & 3] = (unsigned short)(u & 0xffffu);
        lv4[e >> 2][e & 3] = (unsigned short)(u >> 16);
    }
    #pragma unroll
    for (int q2 = 0; q2 < 4; ++q2) {
        *(u16x4*)(hi + base + q2 * 4) = hv4[q2];
        *(u16x4*)(lo + base + q2 * 4) = lv4[q2];
    }
}

// ---- staging helpers (wave-uniform op counts: W slice = 8 glds/wave, x quarter = 11)
__device__ __forceinline__ void stage_w(const unsigned short* __restrict__ wb_all,
                                        char* smem, int woff, int sl, int wid, int l) {
    const char* src = (const char*)wb_all + ((size_t)sl << 15);
    #pragma unroll
    for (int j = 0; j < 8; ++j) {
        const int seg = (j << 12) + (wid << 10);
        __builtin_amdgcn_global_load_lds(
            (const __attribute__((address_space(1))) uint32_t*)(src + seg + l * 16),
            (__attribute__((address_space(3))) uint32_t*)(smem + woff + seg), 16, 0, 0);
    }
    __builtin_amdgcn_sched_barrier(0);
}

__device__ __forceinline__ void stage_x(const unsigned short* __restrict__ hi_in,
                                        const unsigned short* __restrict__ zb,
                                        char* smem, int xoff, int b, int tr, int tc,
                                        int qt, int wid, int l) {
    const int slot_r = l >> 3, sub = l & 7;
    #pragma unroll
    for (int op = 0; op < 11; ++op) {
        const int sbase = (op << 5) + (wid << 3);
        const int s = sbase + slot_r;
        const int rr = (s * 3641) >> 16;      // s/18 for s<=351
        const int hc = s - rr * 18;
        const int h = tr * 16 + rr - 1;
        const int w = tc * 16 + hc - 1;
        const unsigned short* src;
        if ((unsigned)h < 128u && (unsigned)w < 128u)
            src = hi_in + ((((size_t)(b * 128 + h) << 7) + w) << 8) + (qt << 6)
                        + ((sub ^ (s & 7)) << 3);   // swizzle folded into global addr
        else
            src = zb;                                // zero halo
        const int dst = (op == 10 && wid != 0) ? SCR : (xoff + (sbase << 7));
        __builtin_amdgcn_global_load_lds(
            (const __attribute__((address_space(1))) uint32_t*)src,
            (__attribute__((address_space(3))) uint32_t*)(smem + dst), 16, 0, 0);
    }
    __builtin_amdgcn_sched_barrier(0);
}

// ---- main step: 4 waves, 32x32x16 MFMA, 4x4 frags/wave, counted-vmcnt pipeline
__global__ __launch_bounds__(256, 1)
void nca_v5(const unsigned short* __restrict__ hi_in,
            const unsigned short* __restrict__ lo_in,
            const unsigned short* __restrict__ wb,
            const unsigned short* __restrict__ zb,
            const float* __restrict__ mask,
            unsigned short* __restrict__ hi_out,
            unsigned short* __restrict__ lo_out,
            float* __restrict__ out_f32,
            int final_step)
{
    extern __shared__ char smem[];
    const int tid = threadIdx.x;
    const int l = tid & 63, wid = tid >> 6;
    const int wave_o = wid & 1, wave_p = wid >> 1;
    const int lane31 = l & 31, khalf = l >> 5;
    const int col = l & 15, rowin = (l >> 4) & 1;

    int bid = blockIdx.x;
    const int tc = bid & 7; bid >>= 3;
    const int tr = bid & 7; const int b = bid >> 3;

    // mask bits first (before any glds, so vmcnt counts stay exact)
    unsigned long long mbits = 0ull;
    #pragma unroll
    for (int k = 0; k < 9; ++k) {
        #pragma unroll
        for (int n = 0; n < 4; ++n) {
            const int h = tr * 16 + wave_p * 8 + n * 2 + rowin;
            const int w = tc * 16 + col;
            unsigned long long bit = (mask[k * NPIX + h * W_ + w] != 0.f) ? 1ull : 0ull;
            mbits |= bit << (k * 4 + n);
        }
    }
    __builtin_amdgcn_sched_barrier(0);

    // prologue: issue W0, W1, X0, X1   (per-wave vmcnt queue: 8+8+11+11)
    stage_w(wb, smem, WOFF,        0, wid, l);
    stage_w(wb, smem, WOFF + WSL,  1, wid, l);
    stage_x(hi_in, zb, smem, 0,    b, tr, tc, 0, wid, l);
    stage_x(hi_in, zb, smem, XSZ,  b, tr, tc, 1, wid, l);

    int sB[4];
    #pragma unroll
    for (int n = 0; n < 4; ++n) sB[n] = (wave_p * 8 + n * 2 + rowin) * 18 + col;
    int abase[4], aswz[4];
    #pragma unroll
    for (int mo = 0; mo < 4; ++mo) {
        int o_l = wave_o * 128 + mo * 32 + lane31;
        abase[mo] = o_l << 7;
        aswz[mo] = o_l & 7;
    }

    f32x16 zv;
    #pragma unroll
    for (int r = 0; r < 16; ++r) zv[r] = 0.f;
    f32x16 acc[4][4];
    #pragma unroll
    for (int mo = 0; mo < 4; ++mo)
        #pragma unroll
        for (int n = 0; n < 4; ++n) acc[mo][n] = zv;

    #pragma unroll 1
    for (int qt = 0; qt < 4; ++qt) {
        const char* xbuf = smem + ((qt & 1) ? XSZ : 0);
        #pragma unroll 1
        for (int k = 0; k < 9; ++k) {
            const int sl = qt * 9 + k;
            // counted waits: leave newest prefetches in flight, never drain mid-loop
            if (qt == 0 && k <= 1)            asm volatile("s_waitcnt vmcnt(11)" ::: "memory");
            else if (k <= 1 && qt <= 2)       asm volatile("s_waitcnt vmcnt(19)" ::: "memory");
            else if (sl == 35)                asm volatile("s_waitcnt vmcnt(0)"  ::: "memory");
            else                              asm volatile("s_waitcnt vmcnt(8)"  ::: "memory");
            __builtin_amdgcn_sched_barrier(0);
            __builtin_amdgcn_s_barrier();

            const int dy = (k * 11) >> 5;
            const int dx = k - dy * 3;
            const int doff = dy * 18 + dx;
            const char* wbuf = smem + WOFF + ((sl & 1) ? WSL : 0);
            const unsigned mk = (unsigned)(mbits >> (k * 4));

            int sx[4];
            #pragma unroll
            for (int n = 0; n < 4; ++n) sx[n] = sB[n] + doff;

            #pragma unroll
            for (int ks = 0; ks < 4; ++ks) {
                const int ua = ks * 2 + khalf;
                bf16x8 av[4];
                #pragma unroll
                for (int mo = 0; mo < 4; ++mo)
                    av[mo] = *(const bf16x8*)(wbuf + abase[mo] + ((ua ^ aswz[mo]) << 4));
                bf16x8 bv[4];
                #pragma unroll
                for (int n = 0; n < 4; ++n) {
                    i32x4 braw = *(const i32x4*)(xbuf + sx[n] * 128 + ((ua ^ (sx[n] & 7)) << 4));
                    const int mm = -(int)((mk >> n) & 1u);
                    #pragma unroll
                    for (int w4 = 0; w4 < 4; ++w4) braw[w4] &= mm;   // binary mask, exact
                    bv[n] = __builtin_bit_cast(bf16x8, braw);
                }
                #pragma unroll
                for (int mo = 0; mo < 4; ++mo)
                    #pragma unroll
                    for (int n = 0; n < 4; ++n)
                        acc[mo][n] = __builtin_amdgcn_mfma_f32_32x32x16_bf16(av[mo], bv[n], acc[mo][n], 0, 0, 0);
            }

            asm volatile("" ::: "memory");
            __builtin_amdgcn_s_barrier();
            if (sl + 2 < 36)
                stage_w(wb, smem, WOFF + ((sl & 1) ? WSL : 0), sl + 2, wid, l);
            if (k == 8 && qt < 2)
                stage_x(hi_in, zb, smem, (qt & 1) ? XSZ : 0, b, tr, tc, qt + 2, wid, l);
        }
    }

    // ---- epilogue: residual + squash; write hi/lo shadows (or fp32 on final step)
    #pragma unroll
    for (int mo = 0; mo < 4; ++mo) {
        #pragma unroll
        for (int n = 0; n < 4; ++n) {
            const int h = tr * 16 + wave_p * 8 + n * 2 + rowin;
            const int w = tc * 16 + col;
            const size_t pixidx = ((size_t)((b * 128 + h) * 128 + w)) << 8;
            #pragma unroll
            for (int rq = 0; rq < 4; ++rq) {
                const int o0 = wave_o * 128 + mo * 32 + rq * 8 + khalf * 4;
                u16x4 h4 = *(const u16x4*)(hi_in + pixidx + o0);
                u16x4 l4 = *(const u16x4*)(lo_in + pixidx + o0);
                float xn[4];
                #pragma unroll
                for (int r = 0; r < 4; ++r) {
                    float xv = bf2f(h4[r]) + bf2f(l4[r]);
                    float d = acc[mo][n][rq * 4 + r];
                    xn[r] = xv + d / (1.f + fabsf(d));
                }
                if (final_step) {
                    #pragma unroll
                    for (int r = 0; r < 4; ++r)
                        out_f32[((size_t)(b * C_ + o0 + r) * H_ + h) * W_ + w] = xn[r];
                } else {
                    u16x4 ho, lo;
                    #pragma unroll
                    for (int r = 0; r < 4; ++r) {
                        ho[r] = f2bf_rne(xn[r]);
                        lo[r] = f2bf_rne(xn[r] - bf2f(ho[r]));
                    }
                    *(u16x4*)(hi_out + pixidx + o0) = ho;
                    *(u16x4*)(lo_out + pixidx + o0) = lo;
                }
            }
        }
    }
}

// ================= fp32 fallback (only if ws too small) =================
#define OT 64
#define TR 4
#define TC 16
#define CKC 16
__global__ __launch_bounds__(256)
void nca_step_f32(const float* __restrict__ xin, const float* __restrict__ wg,
                  const float* __restrict__ mask, float* __restrict__ xout)
{
    __shared__ __align__(16) float w_s[CKC][9][OT];
    __shared__ __align__(16) float x_s[CKC][TR + 2][20];
    const int tid = threadIdx.x;
    int bt = blockIdx.x;
    const int col_tile = bt & 7;  bt >>= 3;
    const int row_tile = bt & 31; bt >>= 5;
    const int ot = bt & 3;        const int b = bt >> 2;
    const int gr0 = row_tile * TR, gc0 = col_tile * TC, o_base = ot * OT;
    const int og = tid >> 4, pg = tid & 15;
    const int prow = pg >> 2, pcol4 = (pg & 3) * 4;
    const int orow = gr0 + prow, ocol0 = gc0 + pcol4;
    float mask_r[9][4];
#pragma unroll
    for (int k = 0; k < 9; ++k)
#pragma unroll
        for (int j = 0; j < 4; ++j)
            mask_r[k][j] = mask[k * NPIX + orow * W_ + (ocol0 + j)];
    float acc[4][4];
#pragma unroll
    for (int a = 0; a < 4; ++a)
#pragma unroll
        for (int j = 0; j < 4; ++j) acc[a][j] = 0.f;
    for (int chunk = 0; chunk < C_ / CKC; ++chunk) {
        const int c0 = chunk * CKC;
#pragma unroll
        for (int i = 0; i < 36; ++i) {
            const int flat = i * 256 + tid;
            const int o_l = flat / 144;
            const int r = flat - o_l * 144;
            const int c_l = r / 9;
            const int kk = r - c_l * 9;
            w_s[c_l][kk][o_l] = wg[(o_base + o_l) * (C_ * 9) + (c0 + c_l) * 9 + kk];
        }
#pragma unroll
        for (int i = 0; i < 7; ++i) {
            const int flat = i * 256 + tid;
            if (flat < CKC * 108) {
                const int c_l = flat / 108;
                const int r = flat - c_l * 108;
                const int row = r / 18, colx = r - row * 18;
                const int grow = gr0 - 1 + row, gcol = gc0 - 1 + colx;
                float v = 0.f;
                if ((unsigned)grow < (unsigned)H_ && (unsigned)gcol < (unsigned)W_)
                    v = xin[((b * C_ + c0 + c_l) * H_ + grow) * W_ + gcol];
                x_s[c_l][row][colx] = v;
            }
        }
        __syncthreads();
#pragma unroll
        for (int dyy = 0; dyy < 3; ++dyy) {
            float acck[3][4][4];
#pragma unroll
            for (int dxx = 0; dxx < 3; ++dxx)
#pragma unroll
                for (int a = 0; a < 4; ++a)
#pragma unroll
                    for (int j = 0; j < 4; ++j) acck[dxx][a][j] = 0.f;
#pragma unroll 4
            for (int c = 0; c < CKC; ++c) {
                const float4 xv4 = *(const float4*)&x_s[c][prow + dyy][pcol4];
                const float2 xv2 = *(const float2*)&x_s[c][prow + dyy][pcol4 + 4];
                const float xv[6] = {xv4.x, xv4.y, xv4.z, xv4.w, xv2.x, xv2.y};
#pragma unroll
                for (int dxx = 0; dxx < 3; ++dxx) {
                    const float4 wv = *(const float4*)&w_s[c][dyy * 3 + dxx][og * 4];
                    const float wa[4] = {wv.x, wv.y, wv.z, wv.w};
#pragma unroll
                    for (int a = 0; a < 4; ++a)
#pragma unroll
                        for (int j = 0; j < 4; ++j)
                            acck[dxx][a][j] = fmaf(wa[a], xv[j + dxx], acck[dxx][a][j]);
                }
            }
#pragma unroll
            for (int dxx = 0; dxx < 3; ++dxx) {
                const int k = dyy * 3 + dxx;
#pragma unroll
                for (int a = 0; a < 4; ++a)
#pragma unroll
                    for (int j = 0; j < 4; ++j)
                        acc[a][j] = fmaf(mask_r[k][j], acck[dxx][a][j], acc[a][j]);
            }
        }
        __syncthreads();
    }
#pragma unroll
    for (int a = 0; a < 4; ++a) {
        const int o = o_base + og * 4 + a;
#pragma unroll
        for (int j = 0; j < 4; ++j) {
            const int idx = ((b * C_ + o) * H_ + orow) * W_ + (ocol0 + j);
            const float d = acc[a][j];
            xout[idx] = xin[idx] + d / (1.0f + fabsf(d));
        }
    }
}

extern "C" void kernel_launch(void* const* d_in, const int* in_sizes, int n_in,
                              void* d_out, int out_size, void* d_ws, size_t ws_size,
                              hipStream_t stream) {
    const float* retina = (const float*)d_in[0];
    const float* wg     = (const float*)d_in[1];
    const float* mask   = (const float*)d_in[2];
    float* out = (float*)d_out;

    const size_t need = 0x6200000;   // 102,760,448 B: wb+zb (2M) + hiA/loA/loB (3x32M)

    if (ws_size >= need) {
        unsigned short* wb  = (unsigned short*)d_ws;
        unsigned short* zb  = (unsigned short*)((char*)d_ws + 0x120000);
        unsigned short* hiA = (unsigned short*)((char*)d_ws + 0x200000);
        unsigned short* loA = (unsigned short*)((char*)d_ws + 0x2200000);
        unsigned short* loB = (unsigned short*)((char*)d_ws + 0x4200000);
        unsigned short* hiB = (unsigned short*)d_out;   // scratch through step 4

        hipFuncSetAttribute((const void*)nca_v5,
                            hipFuncAttributeMaxDynamicSharedMemorySize, LDS_TOTAL);

        prep_w<<<2305, 256, 0, stream>>>(wg, wb, zb);
        prep_split<<<4096, 256, 0, stream>>>(retina, hiA, loA);

        nca_v5<<<256, 256, LDS_TOTAL, stream>>>(hiA, loA, wb, zb, mask, hiB, loB, out, 0);
        nca_v5<<<256, 256, LDS_TOTAL, stream>>>(hiB, loB, wb, zb, mask, hiA, loA, out, 0);
        nca_v5<<<256, 256, LDS_TOTAL, stream>>>(hiA, loA, wb, zb, mask, hiB, loB, out, 0);
        nca_v5<<<256, 256, LDS_TOTAL, stream>>>(hiB, loB, wb, zb, mask, hiA, loA, out, 0);
        nca_v5<<<256, 256, LDS_TOTAL, stream>>>(hiA, loA, wb, zb, mask, hiA, loA, out, 1);
    } else {
        float* ws = (float*)d_ws;
        const int nblocks = B_ * (C_ / OT) * (H_ / TR) * (W_ / TC);
        const float* src = retina;
        float* dsts[5] = {out, ws, out, ws, out};
        for (int s = 0; s < 5; ++s) {
            nca_step_f32<<<dim3(nblocks), dim3(256), 0, stream>>>(src, wg, mask, dsts[s]);
            src = dsts[s];
        }
    }
}